// Round 3
// baseline (1048.518 us; speedup 1.0000x reference)
//
#include <hip/hip_runtime.h>

#define B_ 32
#define T_ 4096
#define CR 64
#define CS 256
#define NL 20

typedef __bf16 bf16x8 __attribute__((ext_vector_type(8)));
typedef __bf16 bf16x4v __attribute__((ext_vector_type(4)));
typedef float f32x4 __attribute__((ext_vector_type(4)));

__device__ __forceinline__ f32x4 mfma16(bf16x8 a, bf16x8 b, f32x4 c) {
  return __builtin_amdgcn_mfma_f32_16x16x32_bf16(a, b, c, 0, 0, 0);
}

// ---------------- weight pack: fp32 -> bf16, fragment-linear layouts ------
// A-frag semantics: lane l supplies A[m=l&15][k=(l>>4)*8+j].
// Wfg2: [i][mt(4)][fr(8: 0-3=f kc, 4-7=g kc)][lane(64)][8]   (K = tap*64+ci)
// Wr2:  [i][mt(4)][kc(2)][lane(64)][8]                        (K = ci)
// Ws2:  [i][tile(16)][kc(2)][lane(64)][8]                     (K = ci)
// bsS:  sum_i b_s[i][cs]
__global__ void pack_kernel(const float* __restrict__ wf, const float* __restrict__ wg,
                            const float* __restrict__ wsn, const float* __restrict__ wr,
                            const float* __restrict__ bs,
                            __bf16* __restrict__ Wfg2, __bf16* __restrict__ Wr2,
                            __bf16* __restrict__ Ws2, float* __restrict__ bsS) {
  int n = blockIdx.x * 256 + threadIdx.x;
  if (n < 327680) {
    int j = n & 7, lane = (n >> 3) & 63, fr = (n >> 9) & 7, mt = (n >> 12) & 3, i = n >> 14;
    int cs = mt * 16 + (lane & 15);
    int k = (fr & 3) * 32 + (lane >> 4) * 8 + j;
    int ci = k & 63, tap = k >> 6;  // tap0 = delayed tap (conv k=0)
    const float* src = (fr < 4) ? wf : wg;
    Wfg2[n] = (__bf16)src[((i * 64 + cs) * 64 + ci) * 2 + tap];
  } else if (n < 409600) {
    int m = n - 327680;
    int j = m & 7, lane = (m >> 3) & 63, kc = (m >> 9) & 1, mt = (m >> 10) & 3, i = m >> 12;
    int cs = mt * 16 + (lane & 15);
    int ci = kc * 32 + (lane >> 4) * 8 + j;
    Wr2[m] = (__bf16)wr[(i * 64 + cs) * 64 + ci];
  } else if (n < 737280) {
    int m = n - 409600;
    int j = m & 7, lane = (m >> 3) & 63, kc = (m >> 9) & 1, tile = (m >> 10) & 15, i = m >> 14;
    int cs = tile * 16 + (lane & 15);
    int ci = kc * 32 + (lane >> 4) * 8 + j;
    Ws2[m] = (__bf16)wsn[i * 16384 + cs * 64 + ci];
  } else if (n < 737536) {
    int cs = n - 737280;
    float s = 0.f;
    for (int i = 0; i < NL; ++i) s += bs[i * 256 + cs];
    bsS[cs] = s;
  }
}

// ---------------- input 1x1 conv: x[b][ci][t] -> h0[b][t][c] fp32 ----------
__global__ void inconv_kernel(const float* __restrict__ x, const float* __restrict__ w_in,
                              const float* __restrict__ b_in, float* __restrict__ h0) {
  __shared__ float w[64][8];
  __shared__ float bi[64];
  int tid = threadIdx.x;
  for (int k = tid; k < 512; k += 256) w[k >> 3][k & 7] = w_in[k];
  if (tid < 64) bi[tid] = b_in[tid];
  __syncthreads();
  int b = blockIdx.x >> 4;
  int t = ((blockIdx.x & 15) << 8) + tid;
  float xv[8];
#pragma unroll
  for (int ci = 0; ci < 8; ++ci) xv[ci] = x[((size_t)b * 8 + ci) * T_ + t];
  float* orow = h0 + ((size_t)b * T_ + t) * 64;
#pragma unroll
  for (int c0 = 0; c0 < 64; c0 += 4) {
    float s0 = bi[c0], s1 = bi[c0 + 1], s2 = bi[c0 + 2], s3 = bi[c0 + 3];
#pragma unroll
    for (int ci = 0; ci < 8; ++ci) {
      s0 += w[c0][ci] * xv[ci];
      s1 += w[c0 + 1][ci] * xv[ci];
      s2 += w[c0 + 2][ci] * xv[ci];
      s3 += w[c0 + 3][ci] * xv[ci];
    }
    float4 o = make_float4(s0, s1, s2, s3);
    *(float4*)(orow + c0) = o;
  }
}

// ---------------- one gated residual layer --------------------------------
// h_in/h_out: [b][t][64] fp32.
// Zg: fragment-linear tiles: [tile = b*64+tblk][slot][frag(8)][lane(64)][8]
//   elem (nt,kc,l,j) = Z[t0 + nt*16 + (l&15)][ci = kc*32 + (l>>4)*8 + j],
//   frag index = nt*2+kc. 8KB per tile-slot.
__global__ __launch_bounds__(256) void layer_kernel(
    const float* __restrict__ h_in, float* __restrict__ h_out,
    const __bf16* __restrict__ Wfg, const __bf16* __restrict__ Wr,
    const float* __restrict__ bF, const float* __restrict__ bG,
    const float* __restrict__ bR,
    __bf16* __restrict__ Zg, int d, int il, int Gs) {
  __shared__ __bf16 sB[2][64][72];  // pitch 72 elem = 144B

  const int tid = threadIdx.x;
  const int bid = ((blockIdx.x & 7) << 8) | (blockIdx.x >> 3);  // bijective, 2048%8==0
  const int b = bid >> 6;
  const int t0 = (bid & 63) << 6;
  const float* hbase = h_in + ((size_t)b * T_ + t0) * 64;

  // staging: issue all 8 global loads first, then convert+ds_write
  float4 vc[4], vd[4];
#pragma unroll
  for (int it = 0; it < 4; ++it) {
    int f = (it * 256 + tid) * 4;  // flat fp32 index into 64x64 tile
    int trr = f >> 6, c = f & 63;
    vc[it] = *(const float4*)(hbase + trr * 64 + c);
    int td = t0 + trr - d;
    vd[it] = make_float4(0.f, 0.f, 0.f, 0.f);
    if (td >= 0) vd[it] = *(const float4*)(h_in + ((size_t)b * T_ + td) * 64 + c);
  }
#pragma unroll
  for (int it = 0; it < 4; ++it) {
    int f = (it * 256 + tid) * 4;
    int trr = f >> 6, c = f & 63;
    bf16x4v pc = {(__bf16)vc[it].x, (__bf16)vc[it].y, (__bf16)vc[it].z, (__bf16)vc[it].w};
    *(bf16x4v*)&sB[1][trr][c] = pc;
    bf16x4v pd = {(__bf16)vd[it].x, (__bf16)vd[it].y, (__bf16)vd[it].z, (__bf16)vd[it].w};
    *(bf16x4v*)&sB[0][trr][c] = pd;
  }
  __syncthreads();

  const int lane = tid & 63, wid = tid >> 6;
  const int tl = (wid << 4) | (lane & 15);  // this wave's time rows (n index)
  const int kq = lane >> 4;

  bf16x8 bh[4];  // K = tap*64 + ci: kc0,1 = delayed, kc2,3 = current
  bh[0] = *(const bf16x8*)&sB[0][tl][kq * 8];
  bh[1] = *(const bf16x8*)&sB[0][tl][32 + kq * 8];
  bh[2] = *(const bf16x8*)&sB[1][tl][kq * 8];
  bh[3] = *(const bf16x8*)&sB[1][tl][32 + kq * 8];

  __bf16 (*sZ)[72] = sB[0];  // overlay: each wave reads/writes only its own rows
  __bf16* ztile = Zg + ((size_t)bid * Gs + il) * 4096;  // frag-linear dest

#pragma unroll
  for (int mt = 0; mt < 4; ++mt) {
    const __bf16* wb = Wfg + (mt * 8) * 512 + lane * 8;
    f32x4 aF = {0.f, 0.f, 0.f, 0.f}, aG = {0.f, 0.f, 0.f, 0.f};
#pragma unroll
    for (int kc = 0; kc < 4; ++kc) {
      aF = mfma16(*(const bf16x8*)(wb + kc * 512), bh[kc], aF);
      aG = mfma16(*(const bf16x8*)(wb + (4 + kc) * 512), bh[kc], aG);
    }
    const int c0 = (mt << 4) + (kq << 2);  // C/D rows (c_out) for this lane
    float4 bfv = *(const float4*)(bF + c0);
    float4 bgv = *(const float4*)(bG + c0);
    float fb[4] = {bfv.x, bfv.y, bfv.z, bfv.w};
    float gb[4] = {bgv.x, bgv.y, bgv.z, bgv.w};
    bf16x4v zv;
#pragma unroll
    for (int r = 0; r < 4; ++r) {
      float fp = aF[r] + fb[r];
      float gp = aG[r] + gb[r];
      float e = __expf(2.f * fp);
      float th = 1.f - 2.f / (e + 1.f);      // tanh, inf-safe
      float sg = 1.f / (1.f + __expf(-gp));  // sigmoid
      zv[r] = (__bf16)(th * sg);
    }
    *(bf16x4v*)&sZ[tl][c0] = zv;
    // fragment-linear Zg store: nt = wid; ci = c0 + r
    {
      const int kc = mt >> 1;
      const int l = ((mt & 1) * 2 + (kq >> 1)) * 16 + (lane & 15);
      const int j0 = (kq & 1) * 4;
      *(bf16x4v*)(ztile + (size_t)(wid * 2 + kc) * 512 + l * 8 + j0) = zv;
    }
  }

  // residual GEMM: wave-private rows of sZ (no cross-wave -> no barrier)
  bf16x8 bz0 = *(const bf16x8*)&sZ[tl][kq * 8];
  bf16x8 bz1 = *(const bf16x8*)&sZ[tl][32 + kq * 8];
#pragma unroll
  for (int mt = 0; mt < 4; ++mt) {
    const __bf16* wrb = Wr + (mt * 2) * 512 + lane * 8;
    f32x4 aR = {0.f, 0.f, 0.f, 0.f};
    aR = mfma16(*(const bf16x8*)(wrb), bz0, aR);
    aR = mfma16(*(const bf16x8*)(wrb + 512), bz1, aR);
    const int c0 = (mt << 4) + (kq << 2);
    float4 hv = *(const float4*)(h_in + ((size_t)b * T_ + t0 + tl) * 64 + c0);  // L1 hot
    float4 brv = *(const float4*)(bR + c0);
    float4 o;
    o.x = hv.x + aR[0] + brv.x;
    o.y = hv.y + aR[1] + brv.y;
    o.z = hv.z + aR[2] + brv.z;
    o.w = hv.w + aR[3] + brv.w;
    *(float4*)(h_out + ((size_t)b * T_ + t0 + tl) * 64 + c0) = o;
  }
}

// ---------------- grouped skip GEMM: out[b][cs][t] (+)= Z . Ws^T ----------
// Barrier-free: Zg is fragment-linear, so each lane loads its B-fragment
// DIRECTLY global->register (16B/lane, 1KB/frag coalesced). No LDS, no DMA,
// no syncs -- waves slip freely, TLP hides Z latency. 32t x 256cs per block
// (acc = 32 AGPR) -> ~4 waves/SIMD occupancy. W (640KB total) is L2-hot.
__global__ __launch_bounds__(256) void skip_kernel(
    const __bf16* __restrict__ Zg, const __bf16* __restrict__ Ws2,
    const float* __restrict__ bsS, float* __restrict__ out,
    int i0, int cnt, int Gs, int first) {
  const int tid = threadIdx.x;
  const int bx = blockIdx.x;
  const int b = bx >> 7;
  const int t64 = (bx >> 1) & 63;
  const int h = bx & 1;  // which 32-row half of the 64-row Zg tile
  const int t0 = (t64 << 6) + (h << 5);
  const int lane = tid & 63, wid = tid >> 6;
  const int kq = lane >> 4;

  // frags h*4 .. h*4+3 of each 8-frag tile (nt_local*2+kc)
  const __bf16* zb = Zg + ((size_t)(b * 64 + t64) * Gs + i0) * 4096 + h * 2048 + lane * 8;
  const __bf16* wb = Ws2 + (size_t)i0 * 16384 + (size_t)(wid * 8) * 512 + lane * 8;

  f32x4 acc[8];
#pragma unroll
  for (int q = 0; q < 8; ++q) acc[q] = (f32x4){0.f, 0.f, 0.f, 0.f};

#pragma unroll 2
  for (int il = 0; il < cnt; ++il) {
    bf16x8 bz[4];
    bf16x8 aw[8];
#pragma unroll
    for (int f = 0; f < 4; ++f)
      bz[f] = *(const bf16x8*)(zb + (size_t)il * 4096 + f * 512);
#pragma unroll
    for (int f = 0; f < 8; ++f)
      aw[f] = *(const bf16x8*)(wb + (size_t)il * 16384 + f * 512);
#pragma unroll
    for (int mt = 0; mt < 4; ++mt) {
#pragma unroll
      for (int nt = 0; nt < 2; ++nt) {
        acc[mt * 2 + nt] = mfma16(aw[mt * 2], bz[nt * 2], acc[mt * 2 + nt]);
        acc[mt * 2 + nt] = mfma16(aw[mt * 2 + 1], bz[nt * 2 + 1], acc[mt * 2 + nt]);
      }
    }
  }

  const int csb = wid * 64 + (kq << 2);
  const int tcol = t0 + (lane & 15);
#pragma unroll
  for (int mt = 0; mt < 4; ++mt) {
#pragma unroll
    for (int nt = 0; nt < 2; ++nt) {
#pragma unroll
      for (int r = 0; r < 4; ++r) {
        int cs = csb + mt * 16 + r;
        size_t idx = ((size_t)b * CS + cs) * T_ + tcol + nt * 16;
        float v = acc[mt * 2 + nt][r];
        if (first) out[idx] = v + bsS[cs];
        else out[idx] += v;
      }
    }
  }
}

extern "C" void kernel_launch(void* const* d_in, const int* in_sizes, int n_in,
                              void* d_out, int out_size, void* d_ws, size_t ws_size,
                              hipStream_t stream) {
  (void)in_sizes; (void)n_in; (void)out_size;
  const float* x    = (const float*)d_in[0];
  const float* w_in = (const float*)d_in[1];
  const float* b_in = (const float*)d_in[2];
  const float* w_f  = (const float*)d_in[3];
  const float* b_f  = (const float*)d_in[4];
  const float* w_g  = (const float*)d_in[5];
  const float* b_g  = (const float*)d_in[6];
  const float* w_s  = (const float*)d_in[7];
  const float* b_s  = (const float*)d_in[8];
  const float* w_r  = (const float*)d_in[9];
  const float* b_r  = (const float*)d_in[10];
  float* out = (float*)d_out;

  char* ws = (char*)d_ws;
  size_t off = 0;
  auto alloc = [&](size_t bytes) -> char* {
    char* p = ws + off;
    off = (off + bytes + 255) & ~(size_t)255;
    return p;
  };
  float* hA = (float*)alloc((size_t)B_ * T_ * 64 * 4);      // 32 MB
  float* hB = (float*)alloc((size_t)B_ * T_ * 64 * 4);      // 32 MB
  __bf16* Wfg2 = (__bf16*)alloc((size_t)NL * 16384 * 2);
  __bf16* Wr2  = (__bf16*)alloc((size_t)NL * 4096 * 2);
  __bf16* Ws2  = (__bf16*)alloc((size_t)NL * 16384 * 2);
  float* bsS = (float*)alloc(CS * 4);

  size_t zslot = (size_t)B_ * T_ * 64 * 2;  // 16 MB per layer slot
  size_t rem = (ws_size > off) ? (ws_size - off) : 0;
  int G = (int)(rem / zslot);
  if (G > NL) G = NL;
  if (G < 1) G = 1;
  __bf16* Zg = (__bf16*)(ws + off);

  hipLaunchKernelGGL(pack_kernel, dim3(2881), dim3(256), 0, stream,
                     w_f, w_g, w_s, w_r, b_s, Wfg2, Wr2, Ws2, bsS);
  hipLaunchKernelGGL(inconv_kernel, dim3(512), dim3(256), 0, stream, x, w_in, b_in, hA);

  float* hc = hA;
  float* hn = hB;
  int i0 = 0;
  for (int i = 0; i < NL; ++i) {
    int il = i - i0;
    hipLaunchKernelGGL(layer_kernel, dim3(B_ * 64), dim3(256), 0, stream,
                       hc, hn, Wfg2 + (size_t)i * 16384, Wr2 + (size_t)i * 4096,
                       b_f + i * 64, b_g + i * 64, b_r + i * 64,
                       Zg, 1 << (i % 10), il, G);
    { float* tmp = hc; hc = hn; hn = tmp; }
    if (il + 1 == G || i == NL - 1) {
      int cnt = il + 1;
      hipLaunchKernelGGL(skip_kernel, dim3(B_ * 128), dim3(256), 0, stream,
                         Zg, Ws2, bsS, out, i0, cnt, G, (i0 == 0) ? 1 : 0);
      i0 = i + 1;
    }
  }
}

// Round 4
// 1030.495 us; speedup vs baseline: 1.0175x; 1.0175x over previous
//
#include <hip/hip_runtime.h>

#define B_ 32
#define T_ 4096
#define CR 64
#define CS 256
#define NL 20

typedef __bf16 bf16x8 __attribute__((ext_vector_type(8)));
typedef __bf16 bf16x4v __attribute__((ext_vector_type(4)));
typedef float f32x4 __attribute__((ext_vector_type(4)));

__device__ __forceinline__ f32x4 mfma16(bf16x8 a, bf16x8 b, f32x4 c) {
  return __builtin_amdgcn_mfma_f32_16x16x32_bf16(a, b, c, 0, 0, 0);
}

// global -> LDS direct DMA, 16B per lane. LDS dest wave-uniform; HW adds lane*16.
__device__ __forceinline__ void dma16(const __bf16* g, __bf16* l) {
  __builtin_amdgcn_global_load_lds(
      (const __attribute__((address_space(1))) unsigned int*)g,
      (__attribute__((address_space(3))) unsigned int*)l, 16, 0, 0);
}

// ---------------- weight pack: fp32 -> bf16, fragment-linear layouts ------
// A-frag semantics: lane l supplies A[m=l&15][k=(l>>4)*8+j].
// Wfg2: [i][mt(4)][fr(8: 0-3=f kc, 4-7=g kc)][lane(64)][8]   (K = tap*64+ci)
// Wr2:  [i][mt(4)][kc(2)][lane(64)][8]                        (K = ci)
// Ws2:  [i][tile(16)][kc(2)][lane(64)][8]                     (K = ci)
// bsS:  sum_i b_s[i][cs]
__global__ void pack_kernel(const float* __restrict__ wf, const float* __restrict__ wg,
                            const float* __restrict__ wsn, const float* __restrict__ wr,
                            const float* __restrict__ bs,
                            __bf16* __restrict__ Wfg2, __bf16* __restrict__ Wr2,
                            __bf16* __restrict__ Ws2, float* __restrict__ bsS) {
  int n = blockIdx.x * 256 + threadIdx.x;
  if (n < 327680) {
    int j = n & 7, lane = (n >> 3) & 63, fr = (n >> 9) & 7, mt = (n >> 12) & 3, i = n >> 14;
    int cs = mt * 16 + (lane & 15);
    int k = (fr & 3) * 32 + (lane >> 4) * 8 + j;
    int ci = k & 63, tap = k >> 6;  // tap0 = delayed tap (conv k=0)
    const float* src = (fr < 4) ? wf : wg;
    Wfg2[n] = (__bf16)src[((i * 64 + cs) * 64 + ci) * 2 + tap];
  } else if (n < 409600) {
    int m = n - 327680;
    int j = m & 7, lane = (m >> 3) & 63, kc = (m >> 9) & 1, mt = (m >> 10) & 3, i = m >> 12;
    int cs = mt * 16 + (lane & 15);
    int ci = kc * 32 + (lane >> 4) * 8 + j;
    Wr2[m] = (__bf16)wr[(i * 64 + cs) * 64 + ci];
  } else if (n < 737280) {
    int m = n - 409600;
    int j = m & 7, lane = (m >> 3) & 63, kc = (m >> 9) & 1, tile = (m >> 10) & 15, i = m >> 14;
    int cs = tile * 16 + (lane & 15);
    int ci = kc * 32 + (lane >> 4) * 8 + j;
    Ws2[m] = (__bf16)wsn[i * 16384 + cs * 64 + ci];
  } else if (n < 737536) {
    int cs = n - 737280;
    float s = 0.f;
    for (int i = 0; i < NL; ++i) s += bs[i * 256 + cs];
    bsS[cs] = s;
  }
}

// ---------------- input 1x1 conv: x[b][ci][t] -> h0[b][t][c] fp32 ----------
__global__ void inconv_kernel(const float* __restrict__ x, const float* __restrict__ w_in,
                              const float* __restrict__ b_in, float* __restrict__ h0) {
  __shared__ float w[64][8];
  __shared__ float bi[64];
  int tid = threadIdx.x;
  for (int k = tid; k < 512; k += 256) w[k >> 3][k & 7] = w_in[k];
  if (tid < 64) bi[tid] = b_in[tid];
  __syncthreads();
  int b = blockIdx.x >> 4;
  int t = ((blockIdx.x & 15) << 8) + tid;
  float xv[8];
#pragma unroll
  for (int ci = 0; ci < 8; ++ci) xv[ci] = x[((size_t)b * 8 + ci) * T_ + t];
  float* orow = h0 + ((size_t)b * T_ + t) * 64;
#pragma unroll
  for (int c0 = 0; c0 < 64; c0 += 4) {
    float s0 = bi[c0], s1 = bi[c0 + 1], s2 = bi[c0 + 2], s3 = bi[c0 + 3];
#pragma unroll
    for (int ci = 0; ci < 8; ++ci) {
      s0 += w[c0][ci] * xv[ci];
      s1 += w[c0 + 1][ci] * xv[ci];
      s2 += w[c0 + 2][ci] * xv[ci];
      s3 += w[c0 + 3][ci] * xv[ci];
    }
    float4 o = make_float4(s0, s1, s2, s3);
    *(float4*)(orow + c0) = o;
  }
}

// ---------------- one gated residual layer --------------------------------
// h_in/h_out: [b][t][64] fp32.
// Zg: fragment-linear tiles: [tile = b*64+tblk][slot][frag(8)][lane(64)][8]
//   elem (nt,kc,l,j) = Z[t0 + nt*16 + (l&15)][ci = kc*32 + (l>>4)*8 + j],
//   frag index = nt*2+kc. 8KB per tile-slot.
__global__ __launch_bounds__(256) void layer_kernel(
    const float* __restrict__ h_in, float* __restrict__ h_out,
    const __bf16* __restrict__ Wfg, const __bf16* __restrict__ Wr,
    const float* __restrict__ bF, const float* __restrict__ bG,
    const float* __restrict__ bR,
    __bf16* __restrict__ Zg, int d, int il, int Gs) {
  __shared__ __bf16 sB[2][64][72];  // pitch 72 elem = 144B

  const int tid = threadIdx.x;
  const int bid = ((blockIdx.x & 7) << 8) | (blockIdx.x >> 3);  // bijective, 2048%8==0
  const int b = bid >> 6;
  const int t0 = (bid & 63) << 6;
  const float* hbase = h_in + ((size_t)b * T_ + t0) * 64;

  // staging: issue all 8 global loads first, then convert+ds_write
  float4 vc[4], vd[4];
#pragma unroll
  for (int it = 0; it < 4; ++it) {
    int f = (it * 256 + tid) * 4;  // flat fp32 index into 64x64 tile
    int trr = f >> 6, c = f & 63;
    vc[it] = *(const float4*)(hbase + trr * 64 + c);
    int td = t0 + trr - d;
    vd[it] = make_float4(0.f, 0.f, 0.f, 0.f);
    if (td >= 0) vd[it] = *(const float4*)(h_in + ((size_t)b * T_ + td) * 64 + c);
  }
#pragma unroll
  for (int it = 0; it < 4; ++it) {
    int f = (it * 256 + tid) * 4;
    int trr = f >> 6, c = f & 63;
    bf16x4v pc = {(__bf16)vc[it].x, (__bf16)vc[it].y, (__bf16)vc[it].z, (__bf16)vc[it].w};
    *(bf16x4v*)&sB[1][trr][c] = pc;
    bf16x4v pd = {(__bf16)vd[it].x, (__bf16)vd[it].y, (__bf16)vd[it].z, (__bf16)vd[it].w};
    *(bf16x4v*)&sB[0][trr][c] = pd;
  }
  __syncthreads();

  const int lane = tid & 63, wid = tid >> 6;
  const int tl = (wid << 4) | (lane & 15);  // this wave's time rows (n index)
  const int kq = lane >> 4;

  bf16x8 bh[4];  // K = tap*64 + ci: kc0,1 = delayed, kc2,3 = current
  bh[0] = *(const bf16x8*)&sB[0][tl][kq * 8];
  bh[1] = *(const bf16x8*)&sB[0][tl][32 + kq * 8];
  bh[2] = *(const bf16x8*)&sB[1][tl][kq * 8];
  bh[3] = *(const bf16x8*)&sB[1][tl][32 + kq * 8];

  __bf16 (*sZ)[72] = sB[0];  // overlay: each wave reads/writes only its own rows
  __bf16* ztile = Zg + ((size_t)bid * Gs + il) * 4096;  // frag-linear dest

#pragma unroll
  for (int mt = 0; mt < 4; ++mt) {
    const __bf16* wb = Wfg + (mt * 8) * 512 + lane * 8;
    f32x4 aF = {0.f, 0.f, 0.f, 0.f}, aG = {0.f, 0.f, 0.f, 0.f};
#pragma unroll
    for (int kc = 0; kc < 4; ++kc) {
      aF = mfma16(*(const bf16x8*)(wb + kc * 512), bh[kc], aF);
      aG = mfma16(*(const bf16x8*)(wb + (4 + kc) * 512), bh[kc], aG);
    }
    const int c0 = (mt << 4) + (kq << 2);  // C/D rows (c_out) for this lane
    float4 bfv = *(const float4*)(bF + c0);
    float4 bgv = *(const float4*)(bG + c0);
    float fb[4] = {bfv.x, bfv.y, bfv.z, bfv.w};
    float gb[4] = {bgv.x, bgv.y, bgv.z, bgv.w};
    bf16x4v zv;
#pragma unroll
    for (int r = 0; r < 4; ++r) {
      float fp = aF[r] + fb[r];
      float gp = aG[r] + gb[r];
      float e = __expf(2.f * fp);
      float th = 1.f - 2.f / (e + 1.f);      // tanh, inf-safe
      float sg = 1.f / (1.f + __expf(-gp));  // sigmoid
      zv[r] = (__bf16)(th * sg);
    }
    *(bf16x4v*)&sZ[tl][c0] = zv;
    // fragment-linear Zg store: nt = wid; ci = c0 + r
    {
      const int kc = mt >> 1;
      const int l = ((mt & 1) * 2 + (kq >> 1)) * 16 + (lane & 15);
      const int j0 = (kq & 1) * 4;
      *(bf16x4v*)(ztile + (size_t)(wid * 2 + kc) * 512 + l * 8 + j0) = zv;
    }
  }

  // residual GEMM: wave-private rows of sZ (no cross-wave -> no barrier)
  bf16x8 bz0 = *(const bf16x8*)&sZ[tl][kq * 8];
  bf16x8 bz1 = *(const bf16x8*)&sZ[tl][32 + kq * 8];
#pragma unroll
  for (int mt = 0; mt < 4; ++mt) {
    const __bf16* wrb = Wr + (mt * 2) * 512 + lane * 8;
    f32x4 aR = {0.f, 0.f, 0.f, 0.f};
    aR = mfma16(*(const bf16x8*)(wrb), bz0, aR);
    aR = mfma16(*(const bf16x8*)(wrb + 512), bz1, aR);
    const int c0 = (mt << 4) + (kq << 2);
    float4 hv = *(const float4*)(h_in + ((size_t)b * T_ + t0 + tl) * 64 + c0);  // L1 hot
    float4 brv = *(const float4*)(bR + c0);
    float4 o;
    o.x = hv.x + aR[0] + brv.x;
    o.y = hv.y + aR[1] + brv.y;
    o.z = hv.z + aR[2] + brv.z;
    o.w = hv.w + aR[3] + brv.w;
    *(float4*)(h_out + ((size_t)b * T_ + t0 + tl) * 64 + c0) = o;
  }
}

// ---------------- grouped skip GEMM: out[b][cs][t] (+)= Z . Ws^T ----------
// R2 structure + depth-3 DMA (4 bufs) + W-before-DMA issue order so the
// compiler's register-dep wait on W(il) retires exactly {DMA(il+1), W(il)}
// and leaves DMA(il+2), W(il+1), DMA(il+3) = 12 vm-ops in flight across
// every barrier. DMA gets ~3 iters (>900cy) of latency tolerance.
__global__ __launch_bounds__(256) void skip_kernel(
    const __bf16* __restrict__ Zg, const __bf16* __restrict__ Ws2,
    const float* __restrict__ bsS, float* __restrict__ out,
    int i0, int cnt, int Gs, int first) {
  __shared__ __bf16 sZ[4][4096];  // 32 KB, 4-deep rotation

  const int tid = threadIdx.x;
  const int b = blockIdx.x >> 6;
  const int t0 = (blockIdx.x & 63) << 6;
  const int lane = tid & 63, wid = tid >> 6;
  const int kq = lane >> 4;

  const __bf16* ztile = Zg + ((size_t)blockIdx.x * Gs + i0) * 4096;
  const __bf16* wbase = Ws2 + (size_t)i0 * 16384 + (size_t)(wid * 8) * 512 + lane * 8;
  __bf16* ldsw = &sZ[0][0] + (size_t)(wid * 2) * 512;  // wave-uniform LDS dest

#define DMA_TILE(ilx, bufx)                                                   \
  do {                                                                        \
    const __bf16* gsrc_ = ztile + (size_t)(ilx) * 4096 + (wid * 2) * 512 + lane * 8; \
    __bf16* ld_ = ldsw + (size_t)(bufx) * 4096;                               \
    dma16(gsrc_, ld_);                                                        \
    dma16(gsrc_ + 512, ld_ + 512);                                            \
  } while (0)

  f32x4 acc[16];
#pragma unroll
  for (int q = 0; q < 16; ++q) acc[q] = (f32x4){0.f, 0.f, 0.f, 0.f};

  bf16x8 awA[8], awB[8];

  // prologue: W(0) FIRST (oldest vm ops), then DMA(0..2)
#pragma unroll
  for (int f = 0; f < 8; ++f) awA[f] = *(const bf16x8*)(wbase + f * 512);
  __builtin_amdgcn_sched_barrier(0);
  DMA_TILE(0, 0);
  int ndma = 1;
  if (cnt > 1) { DMA_TILE(1, 1); ndma = 2; }
  if (cnt > 2) { DMA_TILE(2, 2); ndma = 3; }
  __builtin_amdgcn_sched_barrier(0);
  // retire W(0)+DMA(0); keep DMA(1),DMA(2) in flight
  if (ndma == 3) asm volatile("s_waitcnt vmcnt(4)" ::: "memory");
  else if (ndma == 2) asm volatile("s_waitcnt vmcnt(2)" ::: "memory");
  else asm volatile("s_waitcnt vmcnt(0)" ::: "memory");
  __builtin_amdgcn_s_barrier();
  __builtin_amdgcn_sched_barrier(0);

#define SKIP_STEP(AWU, AWP)                                                   \
  do {                                                                        \
    const bool have1 = (il + 1) < cnt, have3 = (il + 3) < cnt;                \
    if (have1) {                                                              \
      const __bf16* wn_ = wbase + (size_t)(il + 1) * 16384;                   \
      _Pragma("unroll") for (int f = 0; f < 8; ++f)                           \
          AWP[f] = *(const bf16x8*)(wn_ + f * 512);                           \
    }                                                                         \
    __builtin_amdgcn_sched_barrier(0);                                        \
    if (have3) DMA_TILE(il + 3, (il + 3) & 3);                                \
    __builtin_amdgcn_sched_barrier(0);                                        \
    asm volatile("s_waitcnt vmcnt(12)" ::: "memory");                         \
    __builtin_amdgcn_sched_barrier(0);                                        \
    const __bf16* zb_ = &sZ[0][0] + (size_t)(il & 3) * 4096 + lane * 8;       \
    bf16x8 bz[8];                                                             \
    _Pragma("unroll") for (int f = 0; f < 8; ++f)                             \
        bz[f] = *(const bf16x8*)(zb_ + f * 512);                              \
    _Pragma("unroll") for (int mt = 0; mt < 4; ++mt)                          \
        _Pragma("unroll") for (int nt = 0; nt < 4; ++nt) {                    \
      acc[mt * 4 + nt] = mfma16(AWU[mt * 2], bz[nt * 2], acc[mt * 4 + nt]);   \
      acc[mt * 4 + nt] = mfma16(AWU[mt * 2 + 1], bz[nt * 2 + 1], acc[mt * 4 + nt]); \
    }                                                                         \
    if (have1) {                                                              \
      __builtin_amdgcn_sched_barrier(0);                                      \
      __builtin_amdgcn_s_barrier();                                           \
      __builtin_amdgcn_sched_barrier(0);                                      \
    }                                                                         \
  } while (0)

  int il = 0;
  while (true) {
    SKIP_STEP(awA, awB);
    if (++il == cnt) break;
    SKIP_STEP(awB, awA);
    if (++il == cnt) break;
  }

  const int csb = wid * 64 + (kq << 2);
  const int tcol = t0 + (lane & 15);
#pragma unroll
  for (int mt = 0; mt < 4; ++mt) {
#pragma unroll
    for (int nt = 0; nt < 4; ++nt) {
#pragma unroll
      for (int r = 0; r < 4; ++r) {
        int cs = csb + mt * 16 + r;
        size_t idx = ((size_t)b * CS + cs) * T_ + tcol + nt * 16;
        float v = acc[mt * 4 + nt][r];
        if (first) out[idx] = v + bsS[cs];
        else out[idx] += v;
      }
    }
  }
}

extern "C" void kernel_launch(void* const* d_in, const int* in_sizes, int n_in,
                              void* d_out, int out_size, void* d_ws, size_t ws_size,
                              hipStream_t stream) {
  (void)in_sizes; (void)n_in; (void)out_size;
  const float* x    = (const float*)d_in[0];
  const float* w_in = (const float*)d_in[1];
  const float* b_in = (const float*)d_in[2];
  const float* w_f  = (const float*)d_in[3];
  const float* b_f  = (const float*)d_in[4];
  const float* w_g  = (const float*)d_in[5];
  const float* b_g  = (const float*)d_in[6];
  const float* w_s  = (const float*)d_in[7];
  const float* b_s  = (const float*)d_in[8];
  const float* w_r  = (const float*)d_in[9];
  const float* b_r  = (const float*)d_in[10];
  float* out = (float*)d_out;

  char* ws = (char*)d_ws;
  size_t off = 0;
  auto alloc = [&](size_t bytes) -> char* {
    char* p = ws + off;
    off = (off + bytes + 255) & ~(size_t)255;
    return p;
  };
  float* hA = (float*)alloc((size_t)B_ * T_ * 64 * 4);      // 32 MB
  float* hB = (float*)alloc((size_t)B_ * T_ * 64 * 4);      // 32 MB
  __bf16* Wfg2 = (__bf16*)alloc((size_t)NL * 16384 * 2);
  __bf16* Wr2  = (__bf16*)alloc((size_t)NL * 4096 * 2);
  __bf16* Ws2  = (__bf16*)alloc((size_t)NL * 16384 * 2);
  float* bsS = (float*)alloc(CS * 4);

  size_t zslot = (size_t)B_ * T_ * 64 * 2;  // 16 MB per layer slot
  size_t rem = (ws_size > off) ? (ws_size - off) : 0;
  int G = (int)(rem / zslot);
  if (G > NL) G = NL;
  if (G < 1) G = 1;
  __bf16* Zg = (__bf16*)(ws + off);

  hipLaunchKernelGGL(pack_kernel, dim3(2881), dim3(256), 0, stream,
                     w_f, w_g, w_s, w_r, b_s, Wfg2, Wr2, Ws2, bsS);
  hipLaunchKernelGGL(inconv_kernel, dim3(512), dim3(256), 0, stream, x, w_in, b_in, hA);

  float* hc = hA;
  float* hn = hB;
  int i0 = 0;
  for (int i = 0; i < NL; ++i) {
    int il = i - i0;
    hipLaunchKernelGGL(layer_kernel, dim3(B_ * 64), dim3(256), 0, stream,
                       hc, hn, Wfg2 + (size_t)i * 16384, Wr2 + (size_t)i * 4096,
                       b_f + i * 64, b_g + i * 64, b_r + i * 64,
                       Zg, 1 << (i % 10), il, G);
    { float* tmp = hc; hc = hn; hn = tmp; }
    if (il + 1 == G || i == NL - 1) {
      int cnt = il + 1;
      hipLaunchKernelGGL(skip_kernel, dim3(B_ * 64), dim3(256), 0, stream,
                         Zg, Ws2, bsS, out, i0, cnt, G, (i0 == 0) ? 1 : 0);
      i0 = i + 1;
    }
  }
}

// Round 5
// 916.086 us; speedup vs baseline: 1.1446x; 1.1249x over previous
//
#include <hip/hip_runtime.h>

#define B_ 32
#define T_ 4096
#define CR 64
#define CS 256
#define NL 20

typedef __bf16 bf16x8 __attribute__((ext_vector_type(8)));
typedef __bf16 bf16x4v __attribute__((ext_vector_type(4)));
typedef float f32x4 __attribute__((ext_vector_type(4)));

__device__ __forceinline__ f32x4 mfma16(bf16x8 a, bf16x8 b, f32x4 c) {
  return __builtin_amdgcn_mfma_f32_16x16x32_bf16(a, b, c, 0, 0, 0);
}

// global -> LDS direct DMA, 16B per lane. LDS dest wave-uniform; HW adds lane*16.
__device__ __forceinline__ void dma16(const __bf16* g, __bf16* l) {
  __builtin_amdgcn_global_load_lds(
      (const __attribute__((address_space(1))) unsigned int*)g,
      (__attribute__((address_space(3))) unsigned int*)l, 16, 0, 0);
}

// ---------------- weight pack: fp32 -> bf16, fragment-linear layouts ------
// A-frag semantics: lane l supplies A[m=l&15][k=(l>>4)*8+j].
// Wfg2: [i][mt(4)][fr(8: 0-3=f kc, 4-7=g kc)][lane(64)][8]   (K = tap*64+ci)
// Wr2:  [i][mt(4)][kc(2)][lane(64)][8]                        (K = ci)
// Ws2:  [i][tile(16)][kc(2)][lane(64)][8]                     (K = ci)
// bsS:  sum_i b_s[i][cs]
__global__ void pack_kernel(const float* __restrict__ wf, const float* __restrict__ wg,
                            const float* __restrict__ wsn, const float* __restrict__ wr,
                            const float* __restrict__ bs,
                            __bf16* __restrict__ Wfg2, __bf16* __restrict__ Wr2,
                            __bf16* __restrict__ Ws2, float* __restrict__ bsS) {
  int n = blockIdx.x * 256 + threadIdx.x;
  if (n < 327680) {
    int j = n & 7, lane = (n >> 3) & 63, fr = (n >> 9) & 7, mt = (n >> 12) & 3, i = n >> 14;
    int cs = mt * 16 + (lane & 15);
    int k = (fr & 3) * 32 + (lane >> 4) * 8 + j;
    int ci = k & 63, tap = k >> 6;  // tap0 = delayed tap (conv k=0)
    const float* src = (fr < 4) ? wf : wg;
    Wfg2[n] = (__bf16)src[((i * 64 + cs) * 64 + ci) * 2 + tap];
  } else if (n < 409600) {
    int m = n - 327680;
    int j = m & 7, lane = (m >> 3) & 63, kc = (m >> 9) & 1, mt = (m >> 10) & 3, i = m >> 12;
    int cs = mt * 16 + (lane & 15);
    int ci = kc * 32 + (lane >> 4) * 8 + j;
    Wr2[m] = (__bf16)wr[(i * 64 + cs) * 64 + ci];
  } else if (n < 737280) {
    int m = n - 409600;
    int j = m & 7, lane = (m >> 3) & 63, kc = (m >> 9) & 1, tile = (m >> 10) & 15, i = m >> 14;
    int cs = tile * 16 + (lane & 15);
    int ci = kc * 32 + (lane >> 4) * 8 + j;
    Ws2[m] = (__bf16)wsn[i * 16384 + cs * 64 + ci];
  } else if (n < 737536) {
    int cs = n - 737280;
    float s = 0.f;
    for (int i = 0; i < NL; ++i) s += bs[i * 256 + cs];
    bsS[cs] = s;
  }
}

// ---------------- input 1x1 conv: x[b][ci][t] -> h0[b][t][c] fp32 ----------
__global__ void inconv_kernel(const float* __restrict__ x, const float* __restrict__ w_in,
                              const float* __restrict__ b_in, float* __restrict__ h0) {
  __shared__ float w[64][8];
  __shared__ float bi[64];
  int tid = threadIdx.x;
  for (int k = tid; k < 512; k += 256) w[k >> 3][k & 7] = w_in[k];
  if (tid < 64) bi[tid] = b_in[tid];
  __syncthreads();
  int b = blockIdx.x >> 4;
  int t = ((blockIdx.x & 15) << 8) + tid;
  float xv[8];
#pragma unroll
  for (int ci = 0; ci < 8; ++ci) xv[ci] = x[((size_t)b * 8 + ci) * T_ + t];
  float* orow = h0 + ((size_t)b * T_ + t) * 64;
#pragma unroll
  for (int c0 = 0; c0 < 64; c0 += 4) {
    float s0 = bi[c0], s1 = bi[c0 + 1], s2 = bi[c0 + 2], s3 = bi[c0 + 3];
#pragma unroll
    for (int ci = 0; ci < 8; ++ci) {
      s0 += w[c0][ci] * xv[ci];
      s1 += w[c0 + 1][ci] * xv[ci];
      s2 += w[c0 + 2][ci] * xv[ci];
      s3 += w[c0 + 3][ci] * xv[ci];
    }
    float4 o = make_float4(s0, s1, s2, s3);
    *(float4*)(orow + c0) = o;
  }
}

// ---------------- one gated residual layer --------------------------------
// h_in/h_out: [b][t][64] fp32.
// Zg: fragment-linear tiles: [tile = b*64+tblk][slot][frag(8)][lane(64)][8]
//   elem (nt,kc,l,j) = Z[t0 + nt*16 + (l&15)][ci = kc*32 + (l>>4)*8 + j].
// Delayed-tap overlap reuse (d<64): rows [t0-d,t0) staged into sB[0][0..d),
// rows >= d read from sB[1][tl-d] (current tile, never overwritten).
// Saves the redundant 32MB delayed stream for 12 of 20 layers.
__global__ __launch_bounds__(256) void layer_kernel(
    const float* __restrict__ h_in, float* __restrict__ h_out,
    const __bf16* __restrict__ Wfg, const __bf16* __restrict__ Wr,
    const float* __restrict__ bF, const float* __restrict__ bG,
    const float* __restrict__ bR,
    __bf16* __restrict__ Zg, int d, int il, int Gs) {
  __shared__ __bf16 sB[2][64][72];  // pitch 72 elem = 144B

  const int tid = threadIdx.x;
  const int bid = ((blockIdx.x & 7) << 8) | (blockIdx.x >> 3);  // bijective, 2048%8==0
  const int b = bid >> 6;
  const int t0 = (bid & 63) << 6;
  const float* hbase = h_in + ((size_t)b * T_ + t0) * 64;

  // current tile: issue all 4 float4 loads first
  float4 vc[4];
#pragma unroll
  for (int it = 0; it < 4; ++it) {
    int f = (it * 256 + tid) * 4;  // flat fp32 index into 64x64 tile
    vc[it] = *(const float4*)(hbase + f);
  }

  if (d >= 64) {  // full delayed tile (disjoint from current)
    float4 vd[4];
#pragma unroll
    for (int it = 0; it < 4; ++it) {
      int f = (it * 256 + tid) * 4;
      int trr = f >> 6, c = f & 63;
      int td = t0 + trr - d;
      vd[it] = make_float4(0.f, 0.f, 0.f, 0.f);
      if (td >= 0) vd[it] = *(const float4*)(h_in + ((size_t)b * T_ + td) * 64 + c);
    }
#pragma unroll
    for (int it = 0; it < 4; ++it) {
      int f = (it * 256 + tid) * 4;
      int trr = f >> 6, c = f & 63;
      bf16x4v pd = {(__bf16)vd[it].x, (__bf16)vd[it].y, (__bf16)vd[it].z, (__bf16)vd[it].w};
      *(bf16x4v*)&sB[0][trr][c] = pd;
    }
  } else {  // only d missing rows [t0-d, t0)
    for (int f2 = tid; f2 < (d << 4); f2 += 256) {
      int trr = f2 >> 4, c = (f2 & 15) << 2;
      int td = t0 + trr - d;
      float4 u = make_float4(0.f, 0.f, 0.f, 0.f);
      if (td >= 0) u = *(const float4*)(h_in + ((size_t)b * T_ + td) * 64 + c);
      bf16x4v pd = {(__bf16)u.x, (__bf16)u.y, (__bf16)u.z, (__bf16)u.w};
      *(bf16x4v*)&sB[0][trr][c] = pd;
    }
  }

#pragma unroll
  for (int it = 0; it < 4; ++it) {
    int f = (it * 256 + tid) * 4;
    int trr = f >> 6, c = f & 63;
    bf16x4v pc = {(__bf16)vc[it].x, (__bf16)vc[it].y, (__bf16)vc[it].z, (__bf16)vc[it].w};
    *(bf16x4v*)&sB[1][trr][c] = pc;
  }
  __syncthreads();

  const int lane = tid & 63, wid = tid >> 6;
  const int tl = (wid << 4) | (lane & 15);  // this wave's time rows (n index)
  const int kq = lane >> 4;

  // delayed source: sB[0][tl] if tl<d (fetched rows), else sB[1][tl-d] (reuse)
  const __bf16* pdel = (tl < d) ? &sB[0][tl][0] : &sB[1][tl - d][0];
  bf16x8 bh[4];  // K = tap*64 + ci: kc0,1 = delayed, kc2,3 = current
  bh[0] = *(const bf16x8*)(pdel + kq * 8);
  bh[1] = *(const bf16x8*)(pdel + 32 + kq * 8);
  bh[2] = *(const bf16x8*)&sB[1][tl][kq * 8];
  bh[3] = *(const bf16x8*)&sB[1][tl][32 + kq * 8];

  __bf16 (*sZ)[72] = sB[0];  // overlay: each wave reads/writes only its own rows
  __bf16* ztile = Zg + ((size_t)bid * Gs + il) * 4096;  // frag-linear dest

#pragma unroll
  for (int mt = 0; mt < 4; ++mt) {
    const __bf16* wb = Wfg + (mt * 8) * 512 + lane * 8;
    f32x4 aF = {0.f, 0.f, 0.f, 0.f}, aG = {0.f, 0.f, 0.f, 0.f};
#pragma unroll
    for (int kc = 0; kc < 4; ++kc) {
      aF = mfma16(*(const bf16x8*)(wb + kc * 512), bh[kc], aF);
      aG = mfma16(*(const bf16x8*)(wb + (4 + kc) * 512), bh[kc], aG);
    }
    const int c0 = (mt << 4) + (kq << 2);  // C/D rows (c_out) for this lane
    float4 bfv = *(const float4*)(bF + c0);
    float4 bgv = *(const float4*)(bG + c0);
    float fb[4] = {bfv.x, bfv.y, bfv.z, bfv.w};
    float gb[4] = {bgv.x, bgv.y, bgv.z, bgv.w};
    bf16x4v zv;
#pragma unroll
    for (int r = 0; r < 4; ++r) {
      float fp = aF[r] + fb[r];
      float gp = aG[r] + gb[r];
      float e = __expf(2.f * fp);
      float th = 1.f - 2.f / (e + 1.f);      // tanh, inf-safe
      float sg = 1.f / (1.f + __expf(-gp));  // sigmoid
      zv[r] = (__bf16)(th * sg);
    }
    *(bf16x4v*)&sZ[tl][c0] = zv;
    // fragment-linear Zg store: nt = wid; ci = c0 + r
    {
      const int kc = mt >> 1;
      const int l = ((mt & 1) * 2 + (kq >> 1)) * 16 + (lane & 15);
      const int j0 = (kq & 1) * 4;
      *(bf16x4v*)(ztile + (size_t)(wid * 2 + kc) * 512 + l * 8 + j0) = zv;
    }
  }

  // residual GEMM: wave-private rows of sZ (no cross-wave -> no barrier)
  bf16x8 bz0 = *(const bf16x8*)&sZ[tl][kq * 8];
  bf16x8 bz1 = *(const bf16x8*)&sZ[tl][32 + kq * 8];
#pragma unroll
  for (int mt = 0; mt < 4; ++mt) {
    const __bf16* wrb = Wr + (mt * 2) * 512 + lane * 8;
    f32x4 aR = {0.f, 0.f, 0.f, 0.f};
    aR = mfma16(*(const bf16x8*)(wrb), bz0, aR);
    aR = mfma16(*(const bf16x8*)(wrb + 512), bz1, aR);
    const int c0 = (mt << 4) + (kq << 2);
    float4 hv = *(const float4*)(h_in + ((size_t)b * T_ + t0 + tl) * 64 + c0);  // L1 hot
    float4 brv = *(const float4*)(bR + c0);
    float4 o;
    o.x = hv.x + aR[0] + brv.x;
    o.y = hv.y + aR[1] + brv.y;
    o.z = hv.z + aR[2] + brv.z;
    o.w = hv.w + aR[3] + brv.w;
    *(float4*)(h_out + ((size_t)b * T_ + t0 + tl) * 64 + c0) = o;
  }
}

// ---------------- grouped skip GEMM: out[b][cs][t] (+)= Z . Ws^T ----------
// R2-proven structure: Zg fragment-linear -> global_load_lds DMA into LDS,
// ds_read_b128 at lane*16 conflict-free. Depth-2 DMA (3 bufs), W dbuf in
// regs, vmcnt(10) at the barrier (never full drain).
__global__ __launch_bounds__(256) void skip_kernel(
    const __bf16* __restrict__ Zg, const __bf16* __restrict__ Ws2,
    const float* __restrict__ bsS, float* __restrict__ out,
    int i0, int cnt, int Gs, int first) {
  __shared__ __bf16 sZ[3][4096];

  const int tid = threadIdx.x;
  const int b = blockIdx.x >> 6;
  const int t0 = (blockIdx.x & 63) << 6;
  const int lane = tid & 63, wid = tid >> 6;
  const int kq = lane >> 4;

  const __bf16* ztile = Zg + ((size_t)blockIdx.x * Gs + i0) * 4096;
  const __bf16* wbase = Ws2 + (size_t)i0 * 16384 + (size_t)(wid * 8) * 512 + lane * 8;
  __bf16* ldsw = &sZ[0][0] + (size_t)(wid * 2) * 512;  // wave-uniform LDS dest

#define DMA_TILE(ilx, bufx)                                                   \
  do {                                                                        \
    const __bf16* gsrc_ = ztile + (size_t)(ilx) * 4096 + (wid * 2) * 512 + lane * 8; \
    __bf16* ld_ = ldsw + (size_t)(bufx) * 4096;                               \
    dma16(gsrc_, ld_);                                                        \
    dma16(gsrc_ + 512, ld_ + 512);                                            \
  } while (0)

  f32x4 acc[16];
#pragma unroll
  for (int q = 0; q < 16; ++q) acc[q] = (f32x4){0.f, 0.f, 0.f, 0.f};

  bf16x8 awA[8], awB[8];

  // prologue: DMA(0)->buf0, W(0)->awA, DMA(1)->buf1 (order pinned)
  DMA_TILE(0, 0);
  __builtin_amdgcn_sched_barrier(0);
#pragma unroll
  for (int f = 0; f < 8; ++f) awA[f] = *(const bf16x8*)(wbase + f * 512);
  __builtin_amdgcn_sched_barrier(0);
  if (cnt > 1) {
    DMA_TILE(1, 1);
    __builtin_amdgcn_sched_barrier(0);
    asm volatile("s_waitcnt vmcnt(10)" ::: "memory");  // DMA(0) landed
  } else {
    __builtin_amdgcn_sched_barrier(0);
    asm volatile("s_waitcnt vmcnt(8)" ::: "memory");   // DMA(0) landed
  }
  __builtin_amdgcn_s_barrier();
  __builtin_amdgcn_sched_barrier(0);

#define SKIP_STEP(AWU, AWP)                                                   \
  do {                                                                        \
    const bool have1 = (il + 1) < cnt, have2 = (il + 2) < cnt;                \
    if (have2) {                                                              \
      int b2 = cur + 2;                                                       \
      if (b2 >= 3) b2 -= 3;                                                   \
      DMA_TILE(il + 2, b2);                                                   \
    }                                                                         \
    __builtin_amdgcn_sched_barrier(0);                                        \
    if (have1) {                                                              \
      const __bf16* wn_ = wbase + (size_t)(il + 1) * 16384;                   \
      _Pragma("unroll") for (int f = 0; f < 8; ++f)                           \
          AWP[f] = *(const bf16x8*)(wn_ + f * 512);                           \
    }                                                                         \
    const __bf16* zb_ = &sZ[0][0] + (size_t)cur * 4096 + lane * 8;            \
    bf16x8 bz[4];                                                             \
    _Pragma("unroll") for (int f = 0; f < 4; ++f)                             \
        bz[f] = *(const bf16x8*)(zb_ + f * 512);                              \
    _Pragma("unroll") for (int mt = 0; mt < 4; ++mt)                          \
        _Pragma("unroll") for (int nt = 0; nt < 2; ++nt) {                    \
      acc[mt * 4 + nt] = mfma16(AWU[mt * 2], bz[nt * 2], acc[mt * 4 + nt]);   \
      acc[mt * 4 + nt] = mfma16(AWU[mt * 2 + 1], bz[nt * 2 + 1], acc[mt * 4 + nt]); \
    }                                                                         \
    _Pragma("unroll") for (int f = 0; f < 4; ++f)                             \
        bz[f] = *(const bf16x8*)(zb_ + (4 + f) * 512);                        \
    _Pragma("unroll") for (int mt = 0; mt < 4; ++mt)                          \
        _Pragma("unroll") for (int nt = 0; nt < 2; ++nt) {                    \
      acc[mt * 4 + nt + 2] = mfma16(AWU[mt * 2], bz[nt * 2], acc[mt * 4 + nt + 2]); \
      acc[mt * 4 + nt + 2] =                                                  \
          mfma16(AWU[mt * 2 + 1], bz[nt * 2 + 1], acc[mt * 4 + nt + 2]);      \
    }                                                                         \
    if (have1) {                                                              \
      __builtin_amdgcn_sched_barrier(0);                                      \
      asm volatile("s_waitcnt vmcnt(10) lgkmcnt(0)" ::: "memory");            \
      __builtin_amdgcn_s_barrier();                                           \
      __builtin_amdgcn_sched_barrier(0);                                      \
    }                                                                         \
  } while (0)

  int il = 0, cur = 0;
  while (true) {
    SKIP_STEP(awA, awB);
    if (++il == cnt) break;
    cur = (cur == 2) ? 0 : cur + 1;
    SKIP_STEP(awB, awA);
    if (++il == cnt) break;
    cur = (cur == 2) ? 0 : cur + 1;
  }

  const int csb = wid * 64 + (kq << 2);
  const int tcol = t0 + (lane & 15);
#pragma unroll
  for (int mt = 0; mt < 4; ++mt) {
#pragma unroll
    for (int nt = 0; nt < 4; ++nt) {
#pragma unroll
      for (int r = 0; r < 4; ++r) {
        int cs = csb + mt * 16 + r;
        size_t idx = ((size_t)b * CS + cs) * T_ + tcol + nt * 16;
        float v = acc[mt * 4 + nt][r];
        if (first) out[idx] = v + bsS[cs];
        else out[idx] += v;
      }
    }
  }
}

extern "C" void kernel_launch(void* const* d_in, const int* in_sizes, int n_in,
                              void* d_out, int out_size, void* d_ws, size_t ws_size,
                              hipStream_t stream) {
  (void)in_sizes; (void)n_in; (void)out_size;
  const float* x    = (const float*)d_in[0];
  const float* w_in = (const float*)d_in[1];
  const float* b_in = (const float*)d_in[2];
  const float* w_f  = (const float*)d_in[3];
  const float* b_f  = (const float*)d_in[4];
  const float* w_g  = (const float*)d_in[5];
  const float* b_g  = (const float*)d_in[6];
  const float* w_s  = (const float*)d_in[7];
  const float* b_s  = (const float*)d_in[8];
  const float* w_r  = (const float*)d_in[9];
  const float* b_r  = (const float*)d_in[10];
  float* out = (float*)d_out;

  char* ws = (char*)d_ws;
  size_t off = 0;
  auto alloc = [&](size_t bytes) -> char* {
    char* p = ws + off;
    off = (off + bytes + 255) & ~(size_t)255;
    return p;
  };
  float* hA = (float*)alloc((size_t)B_ * T_ * 64 * 4);      // 32 MB
  float* hB = (float*)alloc((size_t)B_ * T_ * 64 * 4);      // 32 MB
  __bf16* Wfg2 = (__bf16*)alloc((size_t)NL * 16384 * 2);
  __bf16* Wr2  = (__bf16*)alloc((size_t)NL * 4096 * 2);
  __bf16* Ws2  = (__bf16*)alloc((size_t)NL * 16384 * 2);
  float* bsS = (float*)alloc(CS * 4);

  size_t zslot = (size_t)B_ * T_ * 64 * 2;  // 16 MB per layer slot
  size_t rem = (ws_size > off) ? (ws_size - off) : 0;
  int G = (int)(rem / zslot);
  if (G > NL) G = NL;
  if (G < 1) G = 1;
  __bf16* Zg = (__bf16*)(ws + off);

  hipLaunchKernelGGL(pack_kernel, dim3(2881), dim3(256), 0, stream,
                     w_f, w_g, w_s, w_r, b_s, Wfg2, Wr2, Ws2, bsS);
  hipLaunchKernelGGL(inconv_kernel, dim3(512), dim3(256), 0, stream, x, w_in, b_in, hA);

  float* hc = hA;
  float* hn = hB;
  int i0 = 0;
  for (int i = 0; i < NL; ++i) {
    int il = i - i0;
    hipLaunchKernelGGL(layer_kernel, dim3(B_ * 64), dim3(256), 0, stream,
                       hc, hn, Wfg2 + (size_t)i * 16384, Wr2 + (size_t)i * 4096,
                       b_f + i * 64, b_g + i * 64, b_r + i * 64,
                       Zg, 1 << (i % 10), il, G);
    { float* tmp = hc; hc = hn; hn = tmp; }
    if (il + 1 == G || i == NL - 1) {
      int cnt = il + 1;
      hipLaunchKernelGGL(skip_kernel, dim3(B_ * 64), dim3(256), 0, stream,
                         Zg, Ws2, bsS, out, i0, cnt, G, (i0 == 0) ? 1 : 0);
      i0 = i + 1;
    }
  }
}

// Round 6
// 873.766 us; speedup vs baseline: 1.2000x; 1.0484x over previous
//
#include <hip/hip_runtime.h>

#define B_ 32
#define T_ 4096
#define CR 64
#define CS 256
#define NL 20

typedef __bf16 bf16x8 __attribute__((ext_vector_type(8)));
typedef __bf16 bf16x4v __attribute__((ext_vector_type(4)));
typedef float f32x4 __attribute__((ext_vector_type(4)));
typedef unsigned int u32x2 __attribute__((ext_vector_type(2)));

__device__ __forceinline__ f32x4 mfma16(bf16x8 a, bf16x8 b, f32x4 c) {
  return __builtin_amdgcn_mfma_f32_16x16x32_bf16(a, b, c, 0, 0, 0);
}

// global -> LDS direct DMA, 16B per lane. LDS dest wave-uniform; HW adds lane*16.
__device__ __forceinline__ void dma16(const __bf16* g, __bf16* l) {
  __builtin_amdgcn_global_load_lds(
      (const __attribute__((address_space(1))) unsigned int*)g,
      (__attribute__((address_space(3))) unsigned int*)l, 16, 0, 0);
}

// ---------------- weight pack: fp32 -> bf16, fragment-linear layouts ------
// A-frag semantics: lane l supplies A[m=l&15][k=(l>>4)*8+j].
// Wfg2: [i][mt(4)][fr(8: 0-3=f kc, 4-7=g kc)][lane(64)][8]   (K = tap*64+ci)
// Wr2:  [i][mt(4)][kc(2)][lane(64)][8]                        (K = ci)
// Ws2:  [i][tile(16)][kc(2)][lane(64)][8]                     (K = ci)
// bsS:  sum_i b_s[i][cs]
__global__ void pack_kernel(const float* __restrict__ wf, const float* __restrict__ wg,
                            const float* __restrict__ wsn, const float* __restrict__ wr,
                            const float* __restrict__ bs,
                            __bf16* __restrict__ Wfg2, __bf16* __restrict__ Wr2,
                            __bf16* __restrict__ Ws2, float* __restrict__ bsS) {
  int n = blockIdx.x * 256 + threadIdx.x;
  if (n < 327680) {
    int j = n & 7, lane = (n >> 3) & 63, fr = (n >> 9) & 7, mt = (n >> 12) & 3, i = n >> 14;
    int cs = mt * 16 + (lane & 15);
    int k = (fr & 3) * 32 + (lane >> 4) * 8 + j;
    int ci = k & 63, tap = k >> 6;  // tap0 = delayed tap (conv k=0)
    const float* src = (fr < 4) ? wf : wg;
    Wfg2[n] = (__bf16)src[((i * 64 + cs) * 64 + ci) * 2 + tap];
  } else if (n < 409600) {
    int m = n - 327680;
    int j = m & 7, lane = (m >> 3) & 63, kc = (m >> 9) & 1, mt = (m >> 10) & 3, i = m >> 12;
    int cs = mt * 16 + (lane & 15);
    int ci = kc * 32 + (lane >> 4) * 8 + j;
    Wr2[m] = (__bf16)wr[(i * 64 + cs) * 64 + ci];
  } else if (n < 737280) {
    int m = n - 409600;
    int j = m & 7, lane = (m >> 3) & 63, kc = (m >> 9) & 1, tile = (m >> 10) & 15, i = m >> 14;
    int cs = tile * 16 + (lane & 15);
    int ci = kc * 32 + (lane >> 4) * 8 + j;
    Ws2[m] = (__bf16)wsn[i * 16384 + cs * 64 + ci];
  } else if (n < 737536) {
    int cs = n - 737280;
    float s = 0.f;
    for (int i = 0; i < NL; ++i) s += bs[i * 256 + cs];
    bsS[cs] = s;
  }
}

// ---------------- input 1x1 conv: x[b][ci][t] -> h0[b][t][c] fp32 ----------
__global__ void inconv_kernel(const float* __restrict__ x, const float* __restrict__ w_in,
                              const float* __restrict__ b_in, float* __restrict__ h0) {
  __shared__ float w[64][8];
  __shared__ float bi[64];
  int tid = threadIdx.x;
  for (int k = tid; k < 512; k += 256) w[k >> 3][k & 7] = w_in[k];
  if (tid < 64) bi[tid] = b_in[tid];
  __syncthreads();
  int b = blockIdx.x >> 4;
  int t = ((blockIdx.x & 15) << 8) + tid;
  float xv[8];
#pragma unroll
  for (int ci = 0; ci < 8; ++ci) xv[ci] = x[((size_t)b * 8 + ci) * T_ + t];
  float* orow = h0 + ((size_t)b * T_ + t) * 64;
#pragma unroll
  for (int c0 = 0; c0 < 64; c0 += 4) {
    float s0 = bi[c0], s1 = bi[c0 + 1], s2 = bi[c0 + 2], s3 = bi[c0 + 3];
#pragma unroll
    for (int ci = 0; ci < 8; ++ci) {
      s0 += w[c0][ci] * xv[ci];
      s1 += w[c0 + 1][ci] * xv[ci];
      s2 += w[c0 + 2][ci] * xv[ci];
      s3 += w[c0 + 3][ci] * xv[ci];
    }
    float4 o = make_float4(s0, s1, s2, s3);
    *(float4*)(orow + c0) = o;
  }
}

// ---------------- one gated residual layer --------------------------------
// h_in/h_out: [b][t][64] fp32.
// Zg: fragment-linear tiles: [tile = b*64+tblk][slot][frag(8)][lane(64)][8]
//   elem (nt,kc,l,j) = Z[t0 + nt*16 + (l&15)][ci = kc*32 + (l>>4)*8 + j].
// Delayed-tap overlap reuse (d<64): rows [t0-d,t0) staged into sB[0][0..d),
// rows >= d read from sB[1][tl-d] (current tile, never overwritten).
// Zg stores are NON-TEMPORAL: written once, read only after all layers run
// (evicted from L3 by then regardless) -> keep L2/L3 for the h ping-pong.
__global__ __launch_bounds__(256) void layer_kernel(
    const float* __restrict__ h_in, float* __restrict__ h_out,
    const __bf16* __restrict__ Wfg, const __bf16* __restrict__ Wr,
    const float* __restrict__ bF, const float* __restrict__ bG,
    const float* __restrict__ bR,
    __bf16* __restrict__ Zg, int d, int il, int Gs, int last) {
  __shared__ __bf16 sB[2][64][72];  // pitch 72 elem = 144B

  const int tid = threadIdx.x;
  const int bid = ((blockIdx.x & 7) << 8) | (blockIdx.x >> 3);  // bijective, 2048%8==0
  const int b = bid >> 6;
  const int t0 = (bid & 63) << 6;
  const float* hbase = h_in + ((size_t)b * T_ + t0) * 64;

  // current tile: issue all 4 float4 loads first
  float4 vc[4];
#pragma unroll
  for (int it = 0; it < 4; ++it) {
    int f = (it * 256 + tid) * 4;  // flat fp32 index into 64x64 tile
    vc[it] = *(const float4*)(hbase + f);
  }

  if (d >= 64) {  // full delayed tile (disjoint from current)
    float4 vd[4];
#pragma unroll
    for (int it = 0; it < 4; ++it) {
      int f = (it * 256 + tid) * 4;
      int trr = f >> 6, c = f & 63;
      int td = t0 + trr - d;
      vd[it] = make_float4(0.f, 0.f, 0.f, 0.f);
      if (td >= 0) vd[it] = *(const float4*)(h_in + ((size_t)b * T_ + td) * 64 + c);
    }
#pragma unroll
    for (int it = 0; it < 4; ++it) {
      int f = (it * 256 + tid) * 4;
      int trr = f >> 6, c = f & 63;
      bf16x4v pd = {(__bf16)vd[it].x, (__bf16)vd[it].y, (__bf16)vd[it].z, (__bf16)vd[it].w};
      *(bf16x4v*)&sB[0][trr][c] = pd;
    }
  } else {  // only d missing rows [t0-d, t0)
    for (int f2 = tid; f2 < (d << 4); f2 += 256) {
      int trr = f2 >> 4, c = (f2 & 15) << 2;
      int td = t0 + trr - d;
      float4 u = make_float4(0.f, 0.f, 0.f, 0.f);
      if (td >= 0) u = *(const float4*)(h_in + ((size_t)b * T_ + td) * 64 + c);
      bf16x4v pd = {(__bf16)u.x, (__bf16)u.y, (__bf16)u.z, (__bf16)u.w};
      *(bf16x4v*)&sB[0][trr][c] = pd;
    }
  }

#pragma unroll
  for (int it = 0; it < 4; ++it) {
    int f = (it * 256 + tid) * 4;
    int trr = f >> 6, c = f & 63;
    bf16x4v pc = {(__bf16)vc[it].x, (__bf16)vc[it].y, (__bf16)vc[it].z, (__bf16)vc[it].w};
    *(bf16x4v*)&sB[1][trr][c] = pc;
  }
  __syncthreads();

  const int lane = tid & 63, wid = tid >> 6;
  const int tl = (wid << 4) | (lane & 15);  // this wave's time rows (n index)
  const int kq = lane >> 4;

  // delayed source: sB[0][tl] if tl<d (fetched rows), else sB[1][tl-d] (reuse)
  const __bf16* pdel = (tl < d) ? &sB[0][tl][0] : &sB[1][tl - d][0];
  bf16x8 bh[4];  // K = tap*64 + ci: kc0,1 = delayed, kc2,3 = current
  bh[0] = *(const bf16x8*)(pdel + kq * 8);
  bh[1] = *(const bf16x8*)(pdel + 32 + kq * 8);
  bh[2] = *(const bf16x8*)&sB[1][tl][kq * 8];
  bh[3] = *(const bf16x8*)&sB[1][tl][32 + kq * 8];

  __bf16 (*sZ)[72] = sB[0];  // overlay: each wave reads/writes only its own rows
  __bf16* ztile = Zg + ((size_t)bid * Gs + il) * 4096;  // frag-linear dest

#pragma unroll
  for (int mt = 0; mt < 4; ++mt) {
    const __bf16* wb = Wfg + (mt * 8) * 512 + lane * 8;
    f32x4 aF = {0.f, 0.f, 0.f, 0.f}, aG = {0.f, 0.f, 0.f, 0.f};
#pragma unroll
    for (int kc = 0; kc < 4; ++kc) {
      aF = mfma16(*(const bf16x8*)(wb + kc * 512), bh[kc], aF);
      aG = mfma16(*(const bf16x8*)(wb + (4 + kc) * 512), bh[kc], aG);
    }
    const int c0 = (mt << 4) + (kq << 2);  // C/D rows (c_out) for this lane
    float4 bfv = *(const float4*)(bF + c0);
    float4 bgv = *(const float4*)(bG + c0);
    float fb[4] = {bfv.x, bfv.y, bfv.z, bfv.w};
    float gb[4] = {bgv.x, bgv.y, bgv.z, bgv.w};
    bf16x4v zv;
#pragma unroll
    for (int r = 0; r < 4; ++r) {
      float fp = aF[r] + fb[r];
      float gp = aG[r] + gb[r];
      float e = __expf(2.f * fp);
      float th = 1.f - 2.f / (e + 1.f);      // tanh, inf-safe
      float sg = 1.f / (1.f + __expf(-gp));  // sigmoid
      zv[r] = (__bf16)(th * sg);
    }
    *(bf16x4v*)&sZ[tl][c0] = zv;
    // fragment-linear Zg store (non-temporal): nt = wid; ci = c0 + r
    {
      const int kc = mt >> 1;
      const int l = ((mt & 1) * 2 + (kq >> 1)) * 16 + (lane & 15);
      const int j0 = (kq & 1) * 4;
      u32x2 zu = __builtin_bit_cast(u32x2, zv);
      __builtin_nontemporal_store(
          zu, (u32x2*)(ztile + (size_t)(wid * 2 + kc) * 512 + l * 8 + j0));
    }
  }

  if (!last) {
    // residual GEMM: wave-private rows of sZ (no cross-wave -> no barrier)
    bf16x8 bz0 = *(const bf16x8*)&sZ[tl][kq * 8];
    bf16x8 bz1 = *(const bf16x8*)&sZ[tl][32 + kq * 8];
#pragma unroll
    for (int mt = 0; mt < 4; ++mt) {
      const __bf16* wrb = Wr + (mt * 2) * 512 + lane * 8;
      f32x4 aR = {0.f, 0.f, 0.f, 0.f};
      aR = mfma16(*(const bf16x8*)(wrb), bz0, aR);
      aR = mfma16(*(const bf16x8*)(wrb + 512), bz1, aR);
      const int c0 = (mt << 4) + (kq << 2);
      float4 hv = *(const float4*)(h_in + ((size_t)b * T_ + t0 + tl) * 64 + c0);  // L1 hot
      float4 brv = *(const float4*)(bR + c0);
      float4 o;
      o.x = hv.x + aR[0] + brv.x;
      o.y = hv.y + aR[1] + brv.y;
      o.z = hv.z + aR[2] + brv.z;
      o.w = hv.w + aR[3] + brv.w;
      *(float4*)(h_out + ((size_t)b * T_ + t0 + tl) * 64 + c0) = o;
    }
  }
}

// ---------------- grouped skip GEMM: out[b][cs][t] (+)= Z . Ws^T ----------
// R2-proven structure: Zg fragment-linear -> global_load_lds DMA into LDS,
// ds_read_b128 at lane*16 conflict-free. Depth-2 DMA (3 bufs), W dbuf in
// regs, vmcnt(10) at the barrier (never full drain). out stores NT.
__global__ __launch_bounds__(256) void skip_kernel(
    const __bf16* __restrict__ Zg, const __bf16* __restrict__ Ws2,
    const float* __restrict__ bsS, float* __restrict__ out,
    int i0, int cnt, int Gs, int first) {
  __shared__ __bf16 sZ[3][4096];

  const int tid = threadIdx.x;
  const int b = blockIdx.x >> 6;
  const int t0 = (blockIdx.x & 63) << 6;
  const int lane = tid & 63, wid = tid >> 6;
  const int kq = lane >> 4;

  const __bf16* ztile = Zg + ((size_t)blockIdx.x * Gs + i0) * 4096;
  const __bf16* wbase = Ws2 + (size_t)i0 * 16384 + (size_t)(wid * 8) * 512 + lane * 8;
  __bf16* ldsw = &sZ[0][0] + (size_t)(wid * 2) * 512;  // wave-uniform LDS dest

#define DMA_TILE(ilx, bufx)                                                   \
  do {                                                                        \
    const __bf16* gsrc_ = ztile + (size_t)(ilx) * 4096 + (wid * 2) * 512 + lane * 8; \
    __bf16* ld_ = ldsw + (size_t)(bufx) * 4096;                               \
    dma16(gsrc_, ld_);                                                        \
    dma16(gsrc_ + 512, ld_ + 512);                                            \
  } while (0)

  f32x4 acc[16];
#pragma unroll
  for (int q = 0; q < 16; ++q) acc[q] = (f32x4){0.f, 0.f, 0.f, 0.f};

  bf16x8 awA[8], awB[8];

  // prologue: DMA(0)->buf0, W(0)->awA, DMA(1)->buf1 (order pinned)
  DMA_TILE(0, 0);
  __builtin_amdgcn_sched_barrier(0);
#pragma unroll
  for (int f = 0; f < 8; ++f) awA[f] = *(const bf16x8*)(wbase + f * 512);
  __builtin_amdgcn_sched_barrier(0);
  if (cnt > 1) {
    DMA_TILE(1, 1);
    __builtin_amdgcn_sched_barrier(0);
    asm volatile("s_waitcnt vmcnt(10)" ::: "memory");  // DMA(0) landed
  } else {
    __builtin_amdgcn_sched_barrier(0);
    asm volatile("s_waitcnt vmcnt(8)" ::: "memory");   // DMA(0) landed
  }
  __builtin_amdgcn_s_barrier();
  __builtin_amdgcn_sched_barrier(0);

#define SKIP_STEP(AWU, AWP)                                                   \
  do {                                                                        \
    const bool have1 = (il + 1) < cnt, have2 = (il + 2) < cnt;                \
    if (have2) {                                                              \
      int b2 = cur + 2;                                                       \
      if (b2 >= 3) b2 -= 3;                                                   \
      DMA_TILE(il + 2, b2);                                                   \
    }                                                                         \
    __builtin_amdgcn_sched_barrier(0);                                        \
    if (have1) {                                                              \
      const __bf16* wn_ = wbase + (size_t)(il + 1) * 16384;                   \
      _Pragma("unroll") for (int f = 0; f < 8; ++f)                           \
          AWP[f] = *(const bf16x8*)(wn_ + f * 512);                           \
    }                                                                         \
    const __bf16* zb_ = &sZ[0][0] + (size_t)cur * 4096 + lane * 8;            \
    bf16x8 bz[4];                                                             \
    _Pragma("unroll") for (int f = 0; f < 4; ++f)                             \
        bz[f] = *(const bf16x8*)(zb_ + f * 512);                              \
    _Pragma("unroll") for (int mt = 0; mt < 4; ++mt)                          \
        _Pragma("unroll") for (int nt = 0; nt < 2; ++nt) {                    \
      acc[mt * 4 + nt] = mfma16(AWU[mt * 2], bz[nt * 2], acc[mt * 4 + nt]);   \
      acc[mt * 4 + nt] = mfma16(AWU[mt * 2 + 1], bz[nt * 2 + 1], acc[mt * 4 + nt]); \
    }                                                                         \
    _Pragma("unroll") for (int f = 0; f < 4; ++f)                             \
        bz[f] = *(const bf16x8*)(zb_ + (4 + f) * 512);                        \
    _Pragma("unroll") for (int mt = 0; mt < 4; ++mt)                          \
        _Pragma("unroll") for (int nt = 0; nt < 2; ++nt) {                    \
      acc[mt * 4 + nt + 2] = mfma16(AWU[mt * 2], bz[nt * 2], acc[mt * 4 + nt + 2]); \
      acc[mt * 4 + nt + 2] =                                                  \
          mfma16(AWU[mt * 2 + 1], bz[nt * 2 + 1], acc[mt * 4 + nt + 2]);      \
    }                                                                         \
    if (have1) {                                                              \
      __builtin_amdgcn_sched_barrier(0);                                      \
      asm volatile("s_waitcnt vmcnt(10) lgkmcnt(0)" ::: "memory");            \
      __builtin_amdgcn_s_barrier();                                           \
      __builtin_amdgcn_sched_barrier(0);                                      \
    }                                                                         \
  } while (0)

  int il = 0, cur = 0;
  while (true) {
    SKIP_STEP(awA, awB);
    if (++il == cnt) break;
    cur = (cur == 2) ? 0 : cur + 1;
    SKIP_STEP(awB, awA);
    if (++il == cnt) break;
    cur = (cur == 2) ? 0 : cur + 1;
  }

  const int csb = wid * 64 + (kq << 2);
  const int tcol = t0 + (lane & 15);
#pragma unroll
  for (int mt = 0; mt < 4; ++mt) {
#pragma unroll
    for (int nt = 0; nt < 4; ++nt) {
#pragma unroll
      for (int r = 0; r < 4; ++r) {
        int cs = csb + mt * 16 + r;
        size_t idx = ((size_t)b * CS + cs) * T_ + tcol + nt * 16;
        float v = acc[mt * 4 + nt][r];
        if (first) __builtin_nontemporal_store(v + bsS[cs], &out[idx]);
        else out[idx] += v;
      }
    }
  }
}

extern "C" void kernel_launch(void* const* d_in, const int* in_sizes, int n_in,
                              void* d_out, int out_size, void* d_ws, size_t ws_size,
                              hipStream_t stream) {
  (void)in_sizes; (void)n_in; (void)out_size;
  const float* x    = (const float*)d_in[0];
  const float* w_in = (const float*)d_in[1];
  const float* b_in = (const float*)d_in[2];
  const float* w_f  = (const float*)d_in[3];
  const float* b_f  = (const float*)d_in[4];
  const float* w_g  = (const float*)d_in[5];
  const float* b_g  = (const float*)d_in[6];
  const float* w_s  = (const float*)d_in[7];
  const float* b_s  = (const float*)d_in[8];
  const float* w_r  = (const float*)d_in[9];
  const float* b_r  = (const float*)d_in[10];
  float* out = (float*)d_out;

  char* ws = (char*)d_ws;
  size_t off = 0;
  auto alloc = [&](size_t bytes) -> char* {
    char* p = ws + off;
    off = (off + bytes + 255) & ~(size_t)255;
    return p;
  };
  float* hA = (float*)alloc((size_t)B_ * T_ * 64 * 4);      // 32 MB
  float* hB = (float*)alloc((size_t)B_ * T_ * 64 * 4);      // 32 MB
  __bf16* Wfg2 = (__bf16*)alloc((size_t)NL * 16384 * 2);
  __bf16* Wr2  = (__bf16*)alloc((size_t)NL * 4096 * 2);
  __bf16* Ws2  = (__bf16*)alloc((size_t)NL * 16384 * 2);
  float* bsS = (float*)alloc(CS * 4);

  size_t zslot = (size_t)B_ * T_ * 64 * 2;  // 16 MB per layer slot
  size_t rem = (ws_size > off) ? (ws_size - off) : 0;
  int G = (int)(rem / zslot);
  if (G > NL) G = NL;
  if (G < 1) G = 1;
  __bf16* Zg = (__bf16*)(ws + off);

  hipLaunchKernelGGL(pack_kernel, dim3(2881), dim3(256), 0, stream,
                     w_f, w_g, w_s, w_r, b_s, Wfg2, Wr2, Ws2, bsS);
  hipLaunchKernelGGL(inconv_kernel, dim3(512), dim3(256), 0, stream, x, w_in, b_in, hA);

  float* hc = hA;
  float* hn = hB;
  int i0 = 0;
  for (int i = 0; i < NL; ++i) {
    int il = i - i0;
    hipLaunchKernelGGL(layer_kernel, dim3(B_ * 64), dim3(256), 0, stream,
                       hc, hn, Wfg2 + (size_t)i * 16384, Wr2 + (size_t)i * 4096,
                       b_f + i * 64, b_g + i * 64, b_r + i * 64,
                       Zg, 1 << (i % 10), il, G, (i == NL - 1) ? 1 : 0);
    { float* tmp = hc; hc = hn; hn = tmp; }
    if (il + 1 == G || i == NL - 1) {
      int cnt = il + 1;
      hipLaunchKernelGGL(skip_kernel, dim3(B_ * 64), dim3(256), 0, stream,
                         Zg, Ws2, bsS, out, i0, cnt, G, (i0 == 0) ? 1 : 0);
      i0 = i + 1;
    }
  }
}